// Round 8
// baseline (294.089 us; speedup 1.0000x reference)
//
#include <hip/hip_runtime.h>
#include <math.h>

#define IN_F 512
#define OUTF 128
#define NEG_SLOPE 0.2f

// proj1 geometry: 128 threads/block, 1 row per thread, W in LDS (broadcast reads)
#define P1T 128

// bucketing geometry
#define NPB 128               // nodes per bucket (dst >> 7)
#define NBMAX 784             // >= ceil(100000/128) = 782
#define EPB 8192              // edges per binning block
#define SRCMASK 0x1FFFF      // 17-bit src (N < 131072)

// ---------------- prep: fold weights + zero bucketTotal ----------------
__global__ void k_prep(const float* __restrict__ fc1, const float* __restrict__ al1,
                       const float* __restrict__ ar1, const float* __restrict__ fc2,
                       const float* __restrict__ al2, const float* __restrict__ ar2,
                       float* __restrict__ wfold, float* __restrict__ w2al,
                       float* __restrict__ w2ar, int* __restrict__ bucketTotal) {
  int t = threadIdx.x;
  if (blockIdx.x == 0) {
    int k = t;  // 512 threads
#pragma unroll
    for (int h = 0; h < 4; ++h) {
      float wl = 0.f, wr = 0.f, wb = 0.f;
#pragma unroll
      for (int j = 0; j < 4; ++j) {
        float wv = fc1[k * 16 + h * 4 + j];
        wl = fmaf(wv, al1[h * 4 + j], wl);
        wr = fmaf(wv, ar1[h * 4 + j], wr);
        wb += wv;
      }
      wfold[k * 12 + h] = wl;       // el weights
      wfold[k * 12 + 4 + h] = wr;   // er weights
      wfold[k * 12 + 8 + h] = 0.25f * wb;  // hbar weights
    }
  } else {
    if (t < 8) {
      int h = t >> 1;
      const float* a = (t & 1) ? ar2 : al2;
      float s = 0.f;
#pragma unroll 16
      for (int c = 0; c < OUTF; ++c) s += fc2[h * OUTF + c] * a[c];
      if (t & 1) w2ar[h] = s; else w2al[h] = s;
    }
    for (int i = t; i < NBMAX; i += 512) bucketTotal[i] = 0;
  }
}

// ---------------- layer 1 projection: W in LDS, x streamed in registers ----------------
#define LOADC(B, C) do { if (ok) { \
    B[0] = *(const float4*)&xr[(C) * 16 + 0];  \
    B[1] = *(const float4*)&xr[(C) * 16 + 4];  \
    B[2] = *(const float4*)&xr[(C) * 16 + 8];  \
    B[3] = *(const float4*)&xr[(C) * 16 + 12]; } } while (0)

#define COMPC(B, C) do { \
    _Pragma("unroll") for (int q = 0; q < 4; ++q) { \
      float xj[4] = {B[q].x, B[q].y, B[q].z, B[q].w}; \
      _Pragma("unroll") for (int j = 0; j < 4; ++j) { \
        const float* wk = &wsh[((C) * 16 + q * 4 + j) * 12]; \
        float4 w0 = *(const float4*)&wk[0]; \
        float4 w1 = *(const float4*)&wk[4]; \
        float4 w2 = *(const float4*)&wk[8]; \
        acc[0] = fmaf(xj[j], w0.x, acc[0]);  acc[1] = fmaf(xj[j], w0.y, acc[1]); \
        acc[2] = fmaf(xj[j], w0.z, acc[2]);  acc[3] = fmaf(xj[j], w0.w, acc[3]); \
        acc[4] = fmaf(xj[j], w1.x, acc[4]);  acc[5] = fmaf(xj[j], w1.y, acc[5]); \
        acc[6] = fmaf(xj[j], w1.z, acc[6]);  acc[7] = fmaf(xj[j], w1.w, acc[7]); \
        acc[8] = fmaf(xj[j], w2.x, acc[8]);  acc[9] = fmaf(xj[j], w2.y, acc[9]); \
        acc[10] = fmaf(xj[j], w2.z, acc[10]); acc[11] = fmaf(xj[j], w2.w, acc[11]); \
      } } } while (0)

__global__ __launch_bounds__(P1T) void k_proj1(
    const float* __restrict__ x, const float* __restrict__ wf,
    float* __restrict__ pk1, float* __restrict__ er1, int n)
{
  __shared__ float wsh[IN_F * 12];   // 24 KB
  const int t = threadIdx.x;
  for (int i = t * 4; i < IN_F * 12; i += P1T * 4)
    *(float4*)&wsh[i] = *(const float4*)&wf[i];
  __syncthreads();

  const int row = blockIdx.x * P1T + t;
  const bool ok = row < n;
  const float* __restrict__ xr = x + (size_t)row * IN_F;
  float acc[12];
#pragma unroll
  for (int c = 0; c < 12; ++c) acc[c] = 0.f;

  float4 z = make_float4(0.f, 0.f, 0.f, 0.f);
  float4 b0[4] = {z, z, z, z}, b1[4] = {z, z, z, z}, b2[4] = {z, z, z, z};

  LOADC(b0, 0);
  LOADC(b1, 1);
  for (int ct = 0; ct < 30; ct += 3) {    // 32 chunks of 16 k, triple-buffered
    LOADC(b2, ct + 2); COMPC(b0, ct);
    LOADC(b0, ct + 3); COMPC(b1, ct + 1);
    LOADC(b1, ct + 4); COMPC(b2, ct + 2);
  }
  COMPC(b0, 30);
  COMPC(b1, 31);

  if (ok) {
    // pk1[row] = {el[4], hb[4]} packed 32B; er1 separate (read per-dst, streamed)
    *(float4*)&pk1[(size_t)row * 8 + 0] = make_float4(acc[0], acc[1], acc[2], acc[3]);
    *(float4*)&pk1[(size_t)row * 8 + 4] = make_float4(acc[8], acc[9], acc[10], acc[11]);
    *(float4*)&er1[(size_t)row * 4] = make_float4(acc[4], acc[5], acc[6], acc[7]);
  }
}

// ---------------- bucket histogram ----------------
__global__ __launch_bounds__(256) void k_bhist(const int* __restrict__ dst,
                                               int* __restrict__ bucketTotal, int e) {
  __shared__ int hist[NBMAX];
  int t = threadIdx.x;
  for (int i = t; i < NBMAX; i += 256) hist[i] = 0;
  __syncthreads();
  int base = blockIdx.x * EPB;
#pragma unroll
  for (int i = 0; i < EPB / 256; ++i) {
    int idx = base + t + i * 256;
    if (idx < e) atomicAdd(&hist[dst[idx] >> 7], 1);
  }
  __syncthreads();
  for (int i = t; i < NBMAX; i += 256)
    if (hist[i] > 0) atomicAdd(&bucketTotal[i], hist[i]);
}

// ---------------- bucket scan (1 block, VT=4) ----------------
__global__ __launch_bounds__(256) void k_bscan(const int* __restrict__ bucketTotal,
                                               int* __restrict__ bucketBase,
                                               int* __restrict__ bucketCursor,
                                               int nb, int e) {
  __shared__ int sums[256];
  int t = threadIdx.x;
  int v[4];
  int s = 0;
#pragma unroll
  for (int j = 0; j < 4; ++j) {
    int id = t * 4 + j;
    int d = (id < nb) ? bucketTotal[id] : 0;
    v[j] = s; s += d;
  }
  sums[t] = s;
  __syncthreads();
  for (int off = 1; off < 256; off <<= 1) {
    int u = (t >= off) ? sums[t - off] : 0;
    __syncthreads();
    sums[t] += u;
    __syncthreads();
  }
  int excl = sums[t] - s;
#pragma unroll
  for (int j = 0; j < 4; ++j) {
    int id = t * 4 + j;
    if (id < nb) { bucketBase[id] = excl + v[j]; bucketCursor[id] = excl + v[j]; }
    if (id == nb) bucketBase[id] = e;
  }
}

// ---------------- binned scatter: block-aggregated reservation ----------------
__global__ __launch_bounds__(256) void k_bscat(const int* __restrict__ src,
                                               const int* __restrict__ dst,
                                               int* __restrict__ bucketCursor,
                                               unsigned* __restrict__ ep, int e) {
  __shared__ int hist[NBMAX];
  __shared__ int base[NBMAX];
  __shared__ int lcur[NBMAX];
  int t = threadIdx.x;
  for (int i = t; i < NBMAX; i += 256) hist[i] = 0;
  __syncthreads();
  int blockBase = blockIdx.x * EPB;
#pragma unroll
  for (int i = 0; i < EPB / 256; ++i) {
    int idx = blockBase + t + i * 256;
    if (idx < e) atomicAdd(&hist[dst[idx] >> 7], 1);
  }
  __syncthreads();
  for (int i = t; i < NBMAX; i += 256) {
    if (hist[i] > 0) base[i] = atomicAdd(&bucketCursor[i], hist[i]);
    lcur[i] = 0;
  }
  __syncthreads();
#pragma unroll
  for (int i = 0; i < EPB / 256; ++i) {
    int idx = blockBase + t + i * 256;
    if (idx < e) {
      int d = dst[idx];
      int b = d >> 7;
      int p = base[b] + atomicAdd(&lcur[b], 1);
      ep[p] = (unsigned)src[idx] | ((unsigned)(d & (NPB - 1)) << 17);
    }
  }
}

// ---------------- layer 1 bucket aggregation + node epilogue ----------------
__global__ __launch_bounds__(256) void k_bagg1(
    const unsigned* __restrict__ ep, const int* __restrict__ bucketBase,
    const float* __restrict__ pk1, const float* __restrict__ er1,
    const float* __restrict__ bias1,
    const float* __restrict__ w2al, const float* __restrict__ w2ar,
    float* __restrict__ pk2, float* __restrict__ er2, int n)
{
  __shared__ float acc[NPB * 8];   // per node: den[4], num[4]
  __shared__ float ers[NPB * 4];
  int t = threadIdx.x;
  int b = blockIdx.x;
  int nodeBase = b * NPB;
  for (int i = t; i < NPB * 8; i += 256) acc[i] = 0.f;
  for (int i = t; i < NPB; i += 256) {
    int node = nodeBase + i;
    float4 v = (node < n) ? *(const float4*)&er1[(size_t)node * 4]
                          : make_float4(0.f, 0.f, 0.f, 0.f);
    *(float4*)&ers[i * 4] = v;
  }
  __syncthreads();
  int beg = bucketBase[b], end = bucketBase[b + 1];
  for (int j = beg + t; j < end; j += 256) {
    unsigned p = ep[j];
    int s = p & SRCMASK;
    int dl = p >> 17;
    float4 el = *(const float4*)&pk1[(size_t)s * 8];       // same 32B block ->
    float4 hb = *(const float4*)&pk1[(size_t)s * 8 + 4];   // one line per edge
    float* a = &acc[dl * 8];
    float eh, w;
    eh = el.x + ers[dl*4+0]; eh = (eh > 0.f) ? eh : NEG_SLOPE * eh; w = __expf(eh);
    atomicAdd(&a[0], w); atomicAdd(&a[4], w * hb.x);
    eh = el.y + ers[dl*4+1]; eh = (eh > 0.f) ? eh : NEG_SLOPE * eh; w = __expf(eh);
    atomicAdd(&a[1], w); atomicAdd(&a[5], w * hb.y);
    eh = el.z + ers[dl*4+2]; eh = (eh > 0.f) ? eh : NEG_SLOPE * eh; w = __expf(eh);
    atomicAdd(&a[2], w); atomicAdd(&a[6], w * hb.z);
    eh = el.w + ers[dl*4+3]; eh = (eh > 0.f) ? eh : NEG_SLOPE * eh; w = __expf(eh);
    atomicAdd(&a[3], w); atomicAdd(&a[7], w * hb.w);
  }
  __syncthreads();
  float mb[4], wl[4], wr[4];
#pragma unroll
  for (int h = 0; h < 4; ++h) {
    mb[h] = 0.25f * (bias1[h*4] + bias1[h*4+1] + bias1[h*4+2] + bias1[h*4+3]);
    wl[h] = w2al[h]; wr[h] = w2ar[h];
  }
  for (int i = t; i < NPB; i += 256) {
    int node = nodeBase + i;
    if (node >= n) continue;
    float pl = 0.f, pr = 0.f, v[4];
#pragma unroll
    for (int h = 0; h < 4; ++h) {
      float den = acc[i * 8 + h];
      float num = acc[i * 8 + 4 + h];
      float vv = (den > 0.f) ? num / den : 0.f;
      vv += mb[h];
      vv = (vv > 0.f) ? vv : 0.f;
      v[h] = vv;
      pl = fmaf(vv, wl[h], pl);
      pr = fmaf(vv, wr[h], pr);
    }
    // pk2[node] = {h2in[4], el2, pad[3]}: bagg2 gathers one line per edge
    *(float4*)&pk2[(size_t)node * 8] = make_float4(v[0], v[1], v[2], v[3]);
    pk2[(size_t)node * 8 + 4] = pl;
    er2[node] = pr;
  }
}

// ---------------- layer 2 bucket aggregation + fused output projection ----------------
__global__ __launch_bounds__(256) void k_bagg2(
    const unsigned* __restrict__ ep, const int* __restrict__ bucketBase,
    const float* __restrict__ pk2, const float* __restrict__ er2,
    const float* __restrict__ w2, const float* __restrict__ bias2,
    float* __restrict__ out, int n)
{
  __shared__ float acc[NPB * 5];   // per node: den, g[4]
  __shared__ float ers2[NPB];
  __shared__ float w2s[4 * OUTF];
  __shared__ float b2s[OUTF];
  int t = threadIdx.x;
  int b = blockIdx.x;
  int nodeBase = b * NPB;
  for (int i = t; i < NPB * 5; i += 256) acc[i] = 0.f;
  for (int i = t; i < NPB; i += 256) {
    int node = nodeBase + i;
    ers2[i] = (node < n) ? er2[node] : 0.f;
  }
  for (int i = t; i < 4 * OUTF; i += 256) w2s[i] = w2[i];
  if (t < OUTF) b2s[t] = bias2[t];
  __syncthreads();
  int beg = bucketBase[b], end = bucketBase[b + 1];
  for (int j = beg + t; j < end; j += 256) {
    unsigned p = ep[j];
    int s = p & SRCMASK;
    int dl = p >> 17;
    const float* __restrict__ ps = &pk2[(size_t)s * 8];
    float4 hv = *(const float4*)ps;
    float eh = ps[4] + ers2[dl];
    eh = (eh > 0.f) ? eh : NEG_SLOPE * eh;
    float w = __expf(eh);
    float* a = &acc[dl * 5];
    atomicAdd(&a[0], w);
    atomicAdd(&a[1], w * hv.x);
    atomicAdd(&a[2], w * hv.y);
    atomicAdd(&a[3], w * hv.z);
    atomicAdd(&a[4], w * hv.w);
  }
  __syncthreads();
  for (int idx = t; idx < NPB * (OUTF / 2); idx += 256) {
    int i = idx >> 6;
    int node = nodeBase + i;
    if (node >= n) continue;
    int c = (idx & 63) * 2;
    float den = acc[i * 5];
    float inv = (den > 0.f) ? 1.0f / den : 0.f;
    float gx = acc[i*5+1] * inv, gy = acc[i*5+2] * inv;
    float gz = acc[i*5+3] * inv, gw = acc[i*5+4] * inv;
    float2 o;
    o.x = gx*w2s[c]   + gy*w2s[OUTF+c]   + gz*w2s[2*OUTF+c]   + gw*w2s[3*OUTF+c]   + b2s[c];
    o.y = gx*w2s[c+1] + gy*w2s[OUTF+c+1] + gz*w2s[2*OUTF+c+1] + gw*w2s[3*OUTF+c+1] + b2s[c+1];
    *(float2*)&out[(size_t)node * OUTF + c] = o;
  }
}

// ---------------- launch ----------------
extern "C" void kernel_launch(void* const* d_in, const int* in_sizes, int n_in,
                              void* d_out, int out_size, void* d_ws, size_t ws_size,
                              hipStream_t stream) {
  const float* nfeats = (const float*)d_in[0];
  const int*   srcp   = (const int*)d_in[2];
  const int*   dstp   = (const int*)d_in[3];
  const float* fc1    = (const float*)d_in[4];
  const float* al1    = (const float*)d_in[5];
  const float* ar1    = (const float*)d_in[6];
  const float* bias1  = (const float*)d_in[7];
  const float* fc2    = (const float*)d_in[8];
  const float* al2    = (const float*)d_in[9];
  const float* ar2    = (const float*)d_in[10];
  const float* bias2  = (const float*)d_in[11];

  const int N = in_sizes[0] / IN_F;     // 100000
  const int E = in_sizes[2];            // 1600000
  const int NB = (N + NPB - 1) / NPB;   // 782

  float* ws   = (float*)d_ws;
  float* pk1  = ws;                          // 8N  {el[4], hb[4]}
  float* er1  = pk1 + (size_t)8 * N;         // 4N
  float* pk2  = er1 + (size_t)4 * N;         // 8N  {h2in[4], el2, pad[3]}
  float* er2  = pk2 + (size_t)8 * N;         // N
  float* wfold= er2 + N;                     // 512*12
  float* w2al = wfold + 512 * 12;            // 4
  float* w2ar = w2al + 4;                    // 4
  int* bucketTotal  = (int*)(w2ar + 4);      // NBMAX
  int* bucketBase   = bucketTotal + NBMAX;   // NBMAX+1
  int* bucketCursor = bucketBase + NBMAX + 1;// NBMAX
  unsigned* ep      = (unsigned*)(bucketCursor + NBMAX);  // E

  const int binBlocks = (E + EPB - 1) / EPB;     // 196
  const int projBlocks = (N + P1T - 1) / P1T;    // 782

  k_prep<<<2, 512, 0, stream>>>(fc1, al1, ar1, fc2, al2, ar2,
                                wfold, w2al, w2ar, bucketTotal);
  k_bhist<<<binBlocks, 256, 0, stream>>>(dstp, bucketTotal, E);
  k_proj1<<<projBlocks, P1T, 0, stream>>>(nfeats, wfold, pk1, er1, N);
  k_bscan<<<1, 256, 0, stream>>>(bucketTotal, bucketBase, bucketCursor, NB, E);
  k_bscat<<<binBlocks, 256, 0, stream>>>(srcp, dstp, bucketCursor, ep, E);
  k_bagg1<<<NB, 256, 0, stream>>>(ep, bucketBase, pk1, er1, bias1,
                                  w2al, w2ar, pk2, er2, N);
  k_bagg2<<<NB, 256, 0, stream>>>(ep, bucketBase, pk2, er2,
                                  fc2, bias2, (float*)d_out, N);
}

// Round 9
// 286.187 us; speedup vs baseline: 1.0276x; 1.0276x over previous
//
#include <hip/hip_runtime.h>
#include <math.h>

#define IN_F 512
#define OUTF 128
#define NEG_SLOPE 0.2f

// proj1 geometry: 128 threads/block, 1 row/thread, x LDS-staged coalesced,
// W in LDS read via same-address broadcast (conflict-free)
#define P1T 128
#define TK 32
#define PITCH 36              // floats per LDS row (16B-aligned, low conflict)

// bucketing geometry
#define NPB 128               // nodes per bucket (dst >> 7)
#define NBMAX 784             // >= ceil(100000/128) = 782
#define EPB 8192              // edges per binning block
#define SRCMASK 0x1FFFF       // 17-bit src (N < 131072)

// ---------------- prep: fold weights + zero bucketTotal ----------------
__global__ void k_prep(const float* __restrict__ fc1, const float* __restrict__ al1,
                       const float* __restrict__ ar1, const float* __restrict__ fc2,
                       const float* __restrict__ al2, const float* __restrict__ ar2,
                       float* __restrict__ wfold, float* __restrict__ w2al,
                       float* __restrict__ w2ar, int* __restrict__ bucketTotal) {
  int t = threadIdx.x;
  if (blockIdx.x == 0) {
    int k = t;  // 512 threads
#pragma unroll
    for (int h = 0; h < 4; ++h) {
      float wl = 0.f, wr = 0.f, wb = 0.f;
#pragma unroll
      for (int j = 0; j < 4; ++j) {
        float wv = fc1[k * 16 + h * 4 + j];
        wl = fmaf(wv, al1[h * 4 + j], wl);
        wr = fmaf(wv, ar1[h * 4 + j], wr);
        wb += wv;
      }
      wfold[k * 12 + h] = wl;       // el weights
      wfold[k * 12 + 4 + h] = wr;   // er weights
      wfold[k * 12 + 8 + h] = 0.25f * wb;  // hbar weights
    }
  } else {
    if (t < 8) {
      int h = t >> 1;
      const float* a = (t & 1) ? ar2 : al2;
      float s = 0.f;
#pragma unroll 16
      for (int c = 0; c < OUTF; ++c) s += fc2[h * OUTF + c] * a[c];
      if (t & 1) w2ar[h] = s; else w2al[h] = s;
    }
    for (int i = t; i < NBMAX; i += 512) bucketTotal[i] = 0;
  }
}

// ---------------- layer 1 projection ----------------
__global__ __launch_bounds__(P1T) void k_proj1(
    const float* __restrict__ x, const float* __restrict__ wf,
    float* __restrict__ pk1, float* __restrict__ er1, int n)
{
  __shared__ float wsh[IN_F * 12];   // 24 KB folded weights
  __shared__ float xs[P1T * PITCH];  // 18.4 KB x tile
  const int t = threadIdx.x;
  const int rowBase = blockIdx.x * P1T;
  const int myRow = rowBase + t;

  for (int i = t * 4; i < IN_F * 12; i += P1T * 4)
    *(float4*)&wsh[i] = *(const float4*)&wf[i];

  float acc[12];
#pragma unroll
  for (int c = 0; c < 12; ++c) acc[c] = 0.f;

  float4 st[8];
#pragma unroll
  for (int i = 0; i < 8; ++i) {                 // prefetch tile 0 (coalesced)
    int f4 = t + i * P1T;
    int rr = f4 >> 3, c4 = (f4 & 7) << 2;
    int row = rowBase + rr;
    st[i] = (row < n) ? *(const float4*)&x[(size_t)row * IN_F + c4]
                      : make_float4(0.f, 0.f, 0.f, 0.f);
  }

  for (int tile = 0; tile < IN_F / TK; ++tile) {
    __syncthreads();                            // xs consumed by previous compute
#pragma unroll
    for (int i = 0; i < 8; ++i) {
      int f4 = t + i * P1T;
      int rr = f4 >> 3, c4 = (f4 & 7) << 2;
      *(float4*)&xs[rr * PITCH + c4] = st[i];
    }
    if (tile + 1 < IN_F / TK) {
      int k0 = (tile + 1) * TK;
#pragma unroll
      for (int i = 0; i < 8; ++i) {
        int f4 = t + i * P1T;
        int rr = f4 >> 3, c4 = (f4 & 7) << 2;
        int row = rowBase + rr;
        st[i] = (row < n) ? *(const float4*)&x[(size_t)row * IN_F + k0 + c4]
                          : make_float4(0.f, 0.f, 0.f, 0.f);
      }
    }
    __syncthreads();
    const int kq0 = tile * TK;
#pragma unroll
    for (int k4 = 0; k4 < 8; ++k4) {
      float4 xv = *(const float4*)&xs[t * PITCH + k4 * 4];
      float xj[4] = {xv.x, xv.y, xv.z, xv.w};
#pragma unroll
      for (int j = 0; j < 4; ++j) {
        const float* wk = &wsh[(kq0 + k4 * 4 + j) * 12];  // same addr all lanes -> broadcast
        float4 w0 = *(const float4*)&wk[0];
        float4 w1 = *(const float4*)&wk[4];
        float4 w2 = *(const float4*)&wk[8];
        acc[0]  = fmaf(xj[j], w0.x, acc[0]);   acc[1]  = fmaf(xj[j], w0.y, acc[1]);
        acc[2]  = fmaf(xj[j], w0.z, acc[2]);   acc[3]  = fmaf(xj[j], w0.w, acc[3]);
        acc[4]  = fmaf(xj[j], w1.x, acc[4]);   acc[5]  = fmaf(xj[j], w1.y, acc[5]);
        acc[6]  = fmaf(xj[j], w1.z, acc[6]);   acc[7]  = fmaf(xj[j], w1.w, acc[7]);
        acc[8]  = fmaf(xj[j], w2.x, acc[8]);   acc[9]  = fmaf(xj[j], w2.y, acc[9]);
        acc[10] = fmaf(xj[j], w2.z, acc[10]);  acc[11] = fmaf(xj[j], w2.w, acc[11]);
      }
    }
  }

  if (myRow < n) {
    // pk1[row] = {el[4], hb[4]} packed 32B; er1 separate
    *(float4*)&pk1[(size_t)myRow * 8 + 0] = make_float4(acc[0], acc[1], acc[2], acc[3]);
    *(float4*)&pk1[(size_t)myRow * 8 + 4] = make_float4(acc[8], acc[9], acc[10], acc[11]);
    *(float4*)&er1[(size_t)myRow * 4] = make_float4(acc[4], acc[5], acc[6], acc[7]);
  }
}

// ---------------- bucket histogram ----------------
__global__ __launch_bounds__(256) void k_bhist(const int* __restrict__ dst,
                                               int* __restrict__ bucketTotal, int e) {
  __shared__ int hist[NBMAX];
  int t = threadIdx.x;
  for (int i = t; i < NBMAX; i += 256) hist[i] = 0;
  __syncthreads();
  int base = blockIdx.x * EPB;
#pragma unroll
  for (int i = 0; i < EPB / 256; ++i) {
    int idx = base + t + i * 256;
    if (idx < e) atomicAdd(&hist[dst[idx] >> 7], 1);
  }
  __syncthreads();
  for (int i = t; i < NBMAX; i += 256)
    if (hist[i] > 0) atomicAdd(&bucketTotal[i], hist[i]);
}

// ---------------- bucket scan (1 block, VT=4) ----------------
__global__ __launch_bounds__(256) void k_bscan(const int* __restrict__ bucketTotal,
                                               int* __restrict__ bucketBase,
                                               int* __restrict__ bucketCursor,
                                               int nb, int e) {
  __shared__ int sums[256];
  int t = threadIdx.x;
  int v[4];
  int s = 0;
#pragma unroll
  for (int j = 0; j < 4; ++j) {
    int id = t * 4 + j;
    int d = (id < nb) ? bucketTotal[id] : 0;
    v[j] = s; s += d;
  }
  sums[t] = s;
  __syncthreads();
  for (int off = 1; off < 256; off <<= 1) {
    int u = (t >= off) ? sums[t - off] : 0;
    __syncthreads();
    sums[t] += u;
    __syncthreads();
  }
  int excl = sums[t] - s;
#pragma unroll
  for (int j = 0; j < 4; ++j) {
    int id = t * 4 + j;
    if (id < nb) { bucketBase[id] = excl + v[j]; bucketCursor[id] = excl + v[j]; }
    if (id == nb) bucketBase[id] = e;
  }
}

// ---------------- binned scatter: block-aggregated reservation ----------------
__global__ __launch_bounds__(256) void k_bscat(const int* __restrict__ src,
                                               const int* __restrict__ dst,
                                               int* __restrict__ bucketCursor,
                                               unsigned* __restrict__ ep, int e) {
  __shared__ int hist[NBMAX];
  __shared__ int base[NBMAX];
  __shared__ int lcur[NBMAX];
  int t = threadIdx.x;
  for (int i = t; i < NBMAX; i += 256) hist[i] = 0;
  __syncthreads();
  int blockBase = blockIdx.x * EPB;
#pragma unroll
  for (int i = 0; i < EPB / 256; ++i) {
    int idx = blockBase + t + i * 256;
    if (idx < e) atomicAdd(&hist[dst[idx] >> 7], 1);
  }
  __syncthreads();
  for (int i = t; i < NBMAX; i += 256) {
    if (hist[i] > 0) base[i] = atomicAdd(&bucketCursor[i], hist[i]);
    lcur[i] = 0;
  }
  __syncthreads();
#pragma unroll
  for (int i = 0; i < EPB / 256; ++i) {
    int idx = blockBase + t + i * 256;
    if (idx < e) {
      int d = dst[idx];
      int b = d >> 7;
      int p = base[b] + atomicAdd(&lcur[b], 1);
      ep[p] = (unsigned)src[idx] | ((unsigned)(d & (NPB - 1)) << 17);
    }
  }
}

// ---------------- layer 1 bucket aggregation + node epilogue ----------------
__global__ __launch_bounds__(256) void k_bagg1(
    const unsigned* __restrict__ ep, const int* __restrict__ bucketBase,
    const float* __restrict__ pk1, const float* __restrict__ er1,
    const float* __restrict__ bias1,
    const float* __restrict__ w2al, const float* __restrict__ w2ar,
    float* __restrict__ pk2, float* __restrict__ er2, int n)
{
  __shared__ float acc[NPB * 8];   // per node: den[4], num[4]
  __shared__ float ers[NPB * 4];
  int t = threadIdx.x;
  int b = blockIdx.x;
  int nodeBase = b * NPB;
  for (int i = t; i < NPB * 8; i += 256) acc[i] = 0.f;
  for (int i = t; i < NPB; i += 256) {
    int node = nodeBase + i;
    float4 v = (node < n) ? *(const float4*)&er1[(size_t)node * 4]
                          : make_float4(0.f, 0.f, 0.f, 0.f);
    *(float4*)&ers[i * 4] = v;
  }
  __syncthreads();
  int beg = bucketBase[b], end = bucketBase[b + 1];
  for (int j = beg + t; j < end; j += 256) {
    unsigned p = ep[j];
    int s = p & SRCMASK;
    int dl = p >> 17;
    float4 el = *(const float4*)&pk1[(size_t)s * 8];       // same 32B block ->
    float4 hb = *(const float4*)&pk1[(size_t)s * 8 + 4];   // one line per edge
    float* a = &acc[dl * 8];
    float eh, w;
    eh = el.x + ers[dl*4+0]; eh = (eh > 0.f) ? eh : NEG_SLOPE * eh; w = __expf(eh);
    atomicAdd(&a[0], w); atomicAdd(&a[4], w * hb.x);
    eh = el.y + ers[dl*4+1]; eh = (eh > 0.f) ? eh : NEG_SLOPE * eh; w = __expf(eh);
    atomicAdd(&a[1], w); atomicAdd(&a[5], w * hb.y);
    eh = el.z + ers[dl*4+2]; eh = (eh > 0.f) ? eh : NEG_SLOPE * eh; w = __expf(eh);
    atomicAdd(&a[2], w); atomicAdd(&a[6], w * hb.z);
    eh = el.w + ers[dl*4+3]; eh = (eh > 0.f) ? eh : NEG_SLOPE * eh; w = __expf(eh);
    atomicAdd(&a[3], w); atomicAdd(&a[7], w * hb.w);
  }
  __syncthreads();
  float mb[4], wl[4], wr[4];
#pragma unroll
  for (int h = 0; h < 4; ++h) {
    mb[h] = 0.25f * (bias1[h*4] + bias1[h*4+1] + bias1[h*4+2] + bias1[h*4+3]);
    wl[h] = w2al[h]; wr[h] = w2ar[h];
  }
  for (int i = t; i < NPB; i += 256) {
    int node = nodeBase + i;
    if (node >= n) continue;
    float pl = 0.f, pr = 0.f, v[4];
#pragma unroll
    for (int h = 0; h < 4; ++h) {
      float den = acc[i * 8 + h];
      float num = acc[i * 8 + 4 + h];
      float vv = (den > 0.f) ? num / den : 0.f;
      vv += mb[h];
      vv = (vv > 0.f) ? vv : 0.f;
      v[h] = vv;
      pl = fmaf(vv, wl[h], pl);
      pr = fmaf(vv, wr[h], pr);
    }
    // pk2[node] = {h2in[4], el2, pad[3]}: bagg2 gathers one line per edge
    *(float4*)&pk2[(size_t)node * 8] = make_float4(v[0], v[1], v[2], v[3]);
    pk2[(size_t)node * 8 + 4] = pl;
    er2[node] = pr;
  }
}

// ---------------- layer 2 bucket aggregation + fused output projection ----------------
__global__ __launch_bounds__(256) void k_bagg2(
    const unsigned* __restrict__ ep, const int* __restrict__ bucketBase,
    const float* __restrict__ pk2, const float* __restrict__ er2,
    const float* __restrict__ w2, const float* __restrict__ bias2,
    float* __restrict__ out, int n)
{
  __shared__ float acc[NPB * 5];   // per node: den, g[4]
  __shared__ float ers2[NPB];
  __shared__ float w2s[4 * OUTF];
  __shared__ float b2s[OUTF];
  int t = threadIdx.x;
  int b = blockIdx.x;
  int nodeBase = b * NPB;
  for (int i = t; i < NPB * 5; i += 256) acc[i] = 0.f;
  for (int i = t; i < NPB; i += 256) {
    int node = nodeBase + i;
    ers2[i] = (node < n) ? er2[node] : 0.f;
  }
  for (int i = t; i < 4 * OUTF; i += 256) w2s[i] = w2[i];
  if (t < OUTF) b2s[t] = bias2[t];
  __syncthreads();
  int beg = bucketBase[b], end = bucketBase[b + 1];
  for (int j = beg + t; j < end; j += 256) {
    unsigned p = ep[j];
    int s = p & SRCMASK;
    int dl = p >> 17;
    const float* __restrict__ ps = &pk2[(size_t)s * 8];
    float4 hv = *(const float4*)ps;
    float eh = ps[4] + ers2[dl];
    eh = (eh > 0.f) ? eh : NEG_SLOPE * eh;
    float w = __expf(eh);
    float* a = &acc[dl * 5];
    atomicAdd(&a[0], w);
    atomicAdd(&a[1], w * hv.x);
    atomicAdd(&a[2], w * hv.y);
    atomicAdd(&a[3], w * hv.z);
    atomicAdd(&a[4], w * hv.w);
  }
  __syncthreads();
  for (int idx = t; idx < NPB * (OUTF / 2); idx += 256) {
    int i = idx >> 6;
    int node = nodeBase + i;
    if (node >= n) continue;
    int c = (idx & 63) * 2;
    float den = acc[i * 5];
    float inv = (den > 0.f) ? 1.0f / den : 0.f;
    float gx = acc[i*5+1] * inv, gy = acc[i*5+2] * inv;
    float gz = acc[i*5+3] * inv, gw = acc[i*5+4] * inv;
    float2 o;
    o.x = gx*w2s[c]   + gy*w2s[OUTF+c]   + gz*w2s[2*OUTF+c]   + gw*w2s[3*OUTF+c]   + b2s[c];
    o.y = gx*w2s[c+1] + gy*w2s[OUTF+c+1] + gz*w2s[2*OUTF+c+1] + gw*w2s[3*OUTF+c+1] + b2s[c+1];
    *(float2*)&out[(size_t)node * OUTF + c] = o;
  }
}

// ---------------- launch ----------------
extern "C" void kernel_launch(void* const* d_in, const int* in_sizes, int n_in,
                              void* d_out, int out_size, void* d_ws, size_t ws_size,
                              hipStream_t stream) {
  const float* nfeats = (const float*)d_in[0];
  const int*   srcp   = (const int*)d_in[2];
  const int*   dstp   = (const int*)d_in[3];
  const float* fc1    = (const float*)d_in[4];
  const float* al1    = (const float*)d_in[5];
  const float* ar1    = (const float*)d_in[6];
  const float* bias1  = (const float*)d_in[7];
  const float* fc2    = (const float*)d_in[8];
  const float* al2    = (const float*)d_in[9];
  const float* ar2    = (const float*)d_in[10];
  const float* bias2  = (const float*)d_in[11];

  const int N = in_sizes[0] / IN_F;     // 100000
  const int E = in_sizes[2];            // 1600000
  const int NB = (N + NPB - 1) / NPB;   // 782

  float* ws   = (float*)d_ws;
  float* pk1  = ws;                          // 8N  {el[4], hb[4]}
  float* er1  = pk1 + (size_t)8 * N;         // 4N
  float* pk2  = er1 + (size_t)4 * N;         // 8N  {h2in[4], el2, pad[3]}
  float* er2  = pk2 + (size_t)8 * N;         // N
  float* wfold= er2 + N;                     // 512*12
  float* w2al = wfold + 512 * 12;            // 4
  float* w2ar = w2al + 4;                    // 4
  int* bucketTotal  = (int*)(w2ar + 4);      // NBMAX
  int* bucketBase   = bucketTotal + NBMAX;   // NBMAX+1
  int* bucketCursor = bucketBase + NBMAX + 1;// NBMAX
  unsigned* ep      = (unsigned*)(bucketCursor + NBMAX);  // E

  const int binBlocks = (E + EPB - 1) / EPB;     // 196
  const int projBlocks = (N + P1T - 1) / P1T;    // 782

  k_prep<<<2, 512, 0, stream>>>(fc1, al1, ar1, fc2, al2, ar2,
                                wfold, w2al, w2ar, bucketTotal);
  k_bhist<<<binBlocks, 256, 0, stream>>>(dstp, bucketTotal, E);
  k_proj1<<<projBlocks, P1T, 0, stream>>>(nfeats, wfold, pk1, er1, N);
  k_bscan<<<1, 256, 0, stream>>>(bucketTotal, bucketBase, bucketCursor, NB, E);
  k_bscat<<<binBlocks, 256, 0, stream>>>(srcp, dstp, bucketCursor, ep, E);
  k_bagg1<<<NB, 256, 0, stream>>>(ep, bucketBase, pk1, er1, bias1,
                                  w2al, w2ar, pk2, er2, N);
  k_bagg2<<<NB, 256, 0, stream>>>(ep, bucketBase, pk2, er2,
                                  fc2, bias2, (float*)d_out, N);
}